// Round 9
// baseline (241.931 us; speedup 1.0000x reference)
//
#include <hip/hip_runtime.h>
#include <stdint.h>

typedef __attribute__((ext_vector_type(8))) __bf16 bf16x8;
typedef __attribute__((ext_vector_type(4))) float f32x4;
typedef __attribute__((ext_vector_type(4))) unsigned short us4;
typedef __attribute__((ext_vector_type(8))) unsigned short us8v;

__device__ __forceinline__ unsigned short f2b(float f){
  unsigned int u = __builtin_bit_cast(unsigned int, f);
  unsigned int r = (u + 0x7fffu + ((u >> 16) & 1u)) >> 16;
  return (unsigned short)r;
}
__device__ __forceinline__ float b2f(unsigned short h){
  unsigned int u = ((unsigned int)h) << 16;
  return __builtin_bit_cast(float, u);
}

#define KDIM 1024
#define NDIM 1024

// ---------------- fused prep: x cast + 5 LDS-tiled transposes ----------------
// Transpose blocks: 32x32 tile, coalesced float4 loads, LDS bounce, coalesced us4 stores.
__global__ __launch_bounds__(256) void k_prep(
    const float* __restrict__ x,   unsigned short* __restrict__ Xbf,
    const float* __restrict__ fqk, unsigned short* __restrict__ FqkT,
    const float* __restrict__ fv,  unsigned short* __restrict__ FvT,
    const float* __restrict__ rqk, unsigned short* __restrict__ RqkT,
    const float* __restrict__ rv,  unsigned short* __restrict__ RvT,
    const float* __restrict__ wo,  unsigned short* __restrict__ WOT)
{
  __shared__ float tile[32][33];
  int blk = blockIdx.x;
  int tid = threadIdx.x;
  if (blk < 4096){
    int idx = blk * 256 + tid;
    float4 v = ((const float4*)x)[idx];
    us4 o; o.x = f2b(v.x); o.y = f2b(v.y); o.z = f2b(v.z); o.w = f2b(v.w);
    ((us4*)Xbf)[idx] = o;
    return;
  }
  int t = blk - 4096;                 // 5120 transpose tiles
  int mid = t >> 10;                  // matrix id
  int within = t & 1023;
  const float* src; unsigned short* dst;
  int b, R, C, tr, tc;
  if (mid < 2){
    src = mid == 0 ? fqk : fv;  dst = mid == 0 ? FqkT : FvT;
    R = 1024; C = 128;
    b = within >> 7; int tw = within & 127; tr = tw >> 2; tc = tw & 3;
  } else {
    src = mid == 2 ? rqk : (mid == 3 ? rv : wo);
    dst = mid == 2 ? RqkT : (mid == 3 ? RvT : WOT);
    R = 1024; C = 1024;
    b = 0; tr = within >> 5; tc = within & 31;
  }
  int r = tid >> 3, c0 = (tid & 7) * 4;
  size_t base = (size_t)b * R * C;
  float4 v = *(const float4*)&src[base + (size_t)(tr*32 + r) * C + tc*32 + c0];
  tile[r][c0+0] = v.x; tile[r][c0+1] = v.y; tile[r][c0+2] = v.z; tile[r][c0+3] = v.w;
  __syncthreads();
  us4 o;
  o.x = f2b(tile[c0+0][r]); o.y = f2b(tile[c0+1][r]);
  o.z = f2b(tile[c0+2][r]); o.w = f2b(tile[c0+3][r]);
  *(us4*)&dst[base + (size_t)(tc*32 + r) * R + tr*32 + c0] = o;
}

// fused mix: h = sum_n w_f[n]*AH[n*128+r]; G[n*128+r] = w_r[n]*h  for Q,K,V
__global__ __launch_bounds__(128) void k_mix(const unsigned short* __restrict__ ahqk,
    const unsigned short* __restrict__ ahv,
    const float* __restrict__ fwq, const float* __restrict__ fwk, const float* __restrict__ fwv,
    const float* __restrict__ rwq, const float* __restrict__ rwk, const float* __restrict__ rwv,
    unsigned short* __restrict__ gq, unsigned short* __restrict__ gk, unsigned short* __restrict__ gv){
  int bs = blockIdx.x; int r = threadIdx.x;
  const unsigned short* aq = ahqk + (size_t)bs * 1024;
  const unsigned short* av = ahv  + (size_t)bs * 1024;
  float hq = 0.f, hk = 0.f, hv = 0.f;
  float fq[8], fk[8], fvv[8], rq[8], rk[8], rvv[8];
  #pragma unroll
  for (int n = 0; n < 8; n++){
    fq[n] = fwq[bs*8+n]; fk[n] = fwk[bs*8+n]; fvv[n] = fwv[bs*8+n];
    rq[n] = rwq[bs*8+n]; rk[n] = rwk[bs*8+n]; rvv[n] = rwv[bs*8+n];
  }
  #pragma unroll
  for (int n = 0; n < 8; n++){
    float a = b2f(aq[n*128 + r]); hq += a * fq[n]; hk += a * fk[n];
    hv += b2f(av[n*128 + r]) * fvv[n];
  }
  #pragma unroll
  for (int n = 0; n < 8; n++){
    gq[(size_t)bs*1024 + n*128 + r] = f2b(rq[n] * hq);
    gk[(size_t)bs*1024 + n*128 + r] = f2b(rk[n] * hk);
    gv[(size_t)bs*1024 + n*128 + r] = f2b(rvv[n] * hv);
  }
}

// Vpack [bh][s][64] -> Vtile [bh][t=s/128][dh][128]
__global__ void k_transpose_v(const unsigned short* __restrict__ Vp, unsigned short* __restrict__ Vt){
  int idx = blockIdx.x * 256 + threadIdx.x;
  int sc = idx & 127, dh = (idx >> 7) & 63, t = (idx >> 13) & 15, bh = idx >> 17;
  Vt[idx] = Vp[((size_t)(bh * 2048 + t * 128 + sc)) * 64 + dh];
}

// ---------------- GEMM: C[M,N] = A[M,K] @ Bt[N,K]^T, bf16 in, f32 acc ----------------

__device__ __forceinline__ void load_lds16(const void* g, void* l){
  __builtin_amdgcn_global_load_lds((const __attribute__((address_space(1))) unsigned int*)g,
                                   (__attribute__((address_space(3))) unsigned int*)l, 16, 0, 0);
}

template<int OUT_MODE, int BN>
__global__ __launch_bounds__(256) void k_gemm_bt3(
    const unsigned short* __restrict__ A0, const unsigned short* __restrict__ B0, void* __restrict__ C0,
    const unsigned short* __restrict__ A1, const unsigned short* __restrict__ B1, void* __restrict__ C1,
    const unsigned short* __restrict__ A2, const unsigned short* __restrict__ B2, void* __restrict__ C2)
{
  __shared__ unsigned short Al[2][128*32];
  __shared__ unsigned short Bl[2][BN*32];
  int job, bid;
  if constexpr (BN == 64){ job = 0; bid = blockIdx.x; }
  else { job = blockIdx.x >> 8; bid = blockIdx.x & 255; }
  const unsigned short* A  = job == 0 ? A0 : (job == 1 ? A1 : A2);
  const unsigned short* Bt = job == 0 ? B0 : (job == 1 ? B1 : B2);
  void* C = job == 0 ? C0 : (job == 1 ? C1 : C2);
  int bx, by;
  if constexpr (BN == 64){ bx = bid & 15; by = bid >> 4; }
  else { bx = bid & 7; by = bid >> 3; }
  int m0 = by * 128, n0 = bx * BN;
  int tid = threadIdx.x, wid = tid >> 6, lane = tid & 63, l15 = lane & 15, g = lane >> 4;
  int wr = wid >> 1, wc = wid & 1;
  constexpr int WCN = BN / 2;
  constexpr int NACC = WCN / 16;

  auto stage = [&](int buf, int kt){
    #pragma unroll
    for (int i = 0; i < 2; i++){
      int c = i * 256 + tid;
      load_lds16(A + (size_t)(m0 + (c >> 2)) * KDIM + kt * 32 + (c & 3) * 8,
                 &Al[buf][(i * 256 + wid * 64) * 8]);
    }
    #pragma unroll
    for (int i = 0; i < BN/64; i++){
      int c = i * 256 + tid;
      load_lds16(Bt + (size_t)(n0 + (c >> 2)) * KDIM + kt * 32 + (c & 3) * 8,
                 &Bl[buf][(i * 256 + wid * 64) * 8]);
    }
  };

  f32x4 acc[4][NACC] = {};

  stage(0, 0);
  __syncthreads();
  int cur = 0;
  const int nk = KDIM / 32;
  for (int kt = 0; kt < nk; ++kt){
    if (kt + 1 < nk) stage(cur ^ 1, kt + 1);
    bf16x8 af[4], bfv[NACC];
    #pragma unroll
    for (int mi = 0; mi < 4; mi++)
      af[mi] = *(const bf16x8*)&Al[cur][(wr*64 + mi*16 + l15) * 32 + g * 8];
    #pragma unroll
    for (int ni = 0; ni < NACC; ni++)
      bfv[ni] = *(const bf16x8*)&Bl[cur][(wc*WCN + ni*16 + l15) * 32 + g * 8];
    #pragma unroll
    for (int mi = 0; mi < 4; mi++)
      #pragma unroll
      for (int ni = 0; ni < NACC; ni++)
        acc[mi][ni] = __builtin_amdgcn_mfma_f32_16x16x32_bf16(af[mi], bfv[ni], acc[mi][ni], 0, 0, 0);
    __syncthreads();
    cur ^= 1;
  }

  #pragma unroll
  for (int mi = 0; mi < 4; mi++){
    #pragma unroll
    for (int reg = 0; reg < 4; reg++){
      int row = m0 + wr*64 + mi*16 + g*4 + reg;
      #pragma unroll
      for (int ni = 0; ni < NACC; ni++){
        int col = n0 + wc*WCN + ni*16 + l15;
        float v = acc[mi][ni][reg];
        if (OUT_MODE == 0){
          ((float*)C)[(size_t)row * NDIM + col] = v;
        } else if (OUT_MODE == 1){
          ((unsigned short*)C)[(size_t)row * NDIM + col] = f2b(v);
        } else {
          int b = row >> 11, s = row & 2047, h = col >> 6, dh = col & 63;
          ((unsigned short*)C)[(((size_t)(b*16 + h)) * 2048 + s) * 64 + dh] = f2b(v);
        }
      }
    }
  }
}

// ---------------- causal flash attention: QBLK=256, 8 waves, LDS-shared K/V ----------------
// Work unit: (bh, qt of 256 rows, chunk of 768 KV cols). 15 slots/bh -> 480 blocks.
// qt<3: 1 chunk, direct out. qt>=3: 2-3 chunks -> f32 partials [256][64]+[256] l.
#define PSTR 72
__global__ __launch_bounds__(512) void k_attn(
    const unsigned short* __restrict__ Qp_, const unsigned short* __restrict__ Kp_,
    const unsigned short* __restrict__ Vt, unsigned short* __restrict__ AO,
    float* __restrict__ Pws)
{
  __shared__ unsigned short Klds[2][4096];
  __shared__ unsigned short Vlds[2][4096];
  __shared__ unsigned short Plds[8][32*PSTR];

  int bh = blockIdx.x / 15;
  int slot = blockIdx.x % 15;
  int qt, c;
  if (slot < 3){ qt = slot; c = 0; }
  else if (slot < 9){ int s = slot - 3; qt = 3 + (s >> 1); c = s & 1; }
  else { int s = slot - 9; qt = 6 + (s >= 3 ? 1 : 0); c = (s >= 3) ? s - 3 : s; }
  int nc = qt < 3 ? 1 : (qt < 6 ? 2 : 3);
  int b = bh >> 4, h = bh & 15;
  int q0 = qt * 256;
  int kv_lo = c * 768;
  int kv_hi = min((c + 1) * 768, q0 + 256);
  int niter = (kv_hi - kv_lo) >> 6;

  int tid = threadIdx.x, w = tid >> 6, lane = tid & 63, l15 = lane & 15, g = lane >> 4;
  const unsigned short* Qw = Qp_ + ((size_t)bh * 2048 + q0 + w*32) * 64;
  const unsigned short* Kb = Kp_ + (size_t)bh * 2048 * 64;
  const unsigned short* Vb = Vt + (size_t)bh * 16 * 64 * 128;
  unsigned short* Pw = &Plds[w][0];

  int srow = tid >> 3, sj = tid & 7;   // staging: 512 thr, 1 b128 each for K and V

  bf16x8 aq[2][2];
  #pragma unroll
  for (int m = 0; m < 2; m++)
    #pragma unroll
    for (int kk = 0; kk < 2; kk++)
      aq[m][kk] = *(const bf16x8*)(Qw + (m*16 + l15)*64 + kk*32 + g*8);

  const float cs = 0.125f * 1.44269504f;
  float l_run[2][4] = {};
  f32x4 acc_o[2][4] = {};

  us8v kA, vA, kB, vB;

  auto issue = [&](us8v& k0, us8v& v0, int kv0){
    k0 = *(const us8v*)(Kb + ((size_t)(kv0 + srow)) * 64 + sj*8);
    int t128 = kv0 >> 7, koff = kv0 & 64;
    v0 = *(const us8v*)(Vb + ((size_t)(t128*64 + srow)) * 128 + koff + sj*8);
  };
  auto put = [&](int buf, us8v k0, us8v v0){
    *(us8v*)&Klds[buf][(sj*64 + srow)*8] = k0;
    *(us8v*)&Vlds[buf][(sj*64 + srow)*8] = v0;
  };
  auto compute = [&](int buf, int kv0){
    f32x4 s[2][4] = {};
    __builtin_amdgcn_s_setprio(1);
    #pragma unroll
    for (int ti = 0; ti < 4; ti++){
      #pragma unroll
      for (int kk = 0; kk < 2; kk++){
        bf16x8 kf = *(const bf16x8*)&Klds[buf][((kk*4 + g)*64 + ti*16 + l15)*8];
        s[0][ti] = __builtin_amdgcn_mfma_f32_16x16x32_bf16(aq[0][kk], kf, s[0][ti], 0, 0, 0);
        s[1][ti] = __builtin_amdgcn_mfma_f32_16x16x32_bf16(aq[1][kk], kf, s[1][ti], 0, 0, 0);
      }
    }
    __builtin_amdgcn_s_setprio(0);
    bool partial = (kv0 + 64 > q0);
    #pragma unroll
    for (int m = 0; m < 2; m++){
      #pragma unroll
      for (int reg = 0; reg < 4; reg++){
        int row = q0 + w*32 + m*16 + g*4 + reg;
        #pragma unroll
        for (int ti = 0; ti < 4; ti++){
          float x = s[m][ti][reg] * cs;
          if (partial){
            int col = kv0 + ti*16 + l15;
            if (col > row) x = -1e30f;
          }
          float p = exp2f(x);
          l_run[m][reg] += p;
          Pw[(m*16 + g*4 + reg)*PSTR + ((ti ^ g)*16) + l15] = f2b(p);
        }
      }
    }
    bf16x8 pa[2][2];
    #pragma unroll
    for (int m = 0; m < 2; m++)
      #pragma unroll
      for (int cc = 0; cc < 2; cc++){
        int tiL = cc*2 + (g >> 1);
        int tiS = tiL ^ ((l15 >> 2) & 3);
        pa[m][cc] = *(const bf16x8*)&Pw[(m*16 + l15)*PSTR + tiS*16 + (g & 1)*8];
      }
    __builtin_amdgcn_s_setprio(1);
    #pragma unroll
    for (int ni = 0; ni < 4; ni++){
      #pragma unroll
      for (int cc = 0; cc < 2; cc++){
        bf16x8 vf = *(const bf16x8*)&Vlds[buf][((cc*4 + g)*64 + ni*16 + l15)*8];
        acc_o[0][ni] = __builtin_amdgcn_mfma_f32_16x16x32_bf16(pa[0][cc], vf, acc_o[0][ni], 0, 0, 0);
        acc_o[1][ni] = __builtin_amdgcn_mfma_f32_16x16x32_bf16(pa[1][cc], vf, acc_o[1][ni], 0, 0, 0);
      }
    }
    __builtin_amdgcn_s_setprio(0);
  };

  issue(kA, vA, kv_lo);
  put(0, kA, vA);
  __syncthreads();
  int it = 0, cur = 0;
  while (true){
    if (it + 1 < niter) issue(kB, vB, kv_lo + (it+1)*64);
    compute(cur, kv_lo + it*64);
    if (it + 1 < niter) put(cur ^ 1, kB, vB);
    __syncthreads();
    cur ^= 1; ++it;
    if (it >= niter) break;
    if (it + 1 < niter) issue(kA, vA, kv_lo + (it+1)*64);
    compute(cur, kv_lo + it*64);
    if (it + 1 < niter) put(cur ^ 1, kA, vA);
    __syncthreads();
    cur ^= 1; ++it;
    if (it >= niter) break;
  }

  #pragma unroll
  for (int m = 0; m < 2; m++)
    #pragma unroll
    for (int reg = 0; reg < 4; reg++){
      #pragma unroll
      for (int off = 1; off < 16; off <<= 1) l_run[m][reg] += __shfl_xor(l_run[m][reg], off);
    }

  if (nc == 1){
    #pragma unroll
    for (int m = 0; m < 2; m++)
      #pragma unroll
      for (int ni = 0; ni < 4; ni++)
        #pragma unroll
        for (int reg = 0; reg < 4; reg++){
          int row = q0 + w*32 + m*16 + g*4 + reg;
          int dh = ni*16 + l15;
          AO[((size_t)(b*2048 + row)) * 1024 + h*64 + dh] = f2b(acc_o[m][ni][reg] / l_run[m][reg]);
        }
  } else {
    float* P0 = Pws + ((size_t)((bh*5 + (qt - 3))*3 + c)) * (256*65);
    #pragma unroll
    for (int m = 0; m < 2; m++)
      #pragma unroll
      for (int ni = 0; ni < 4; ni++)
        #pragma unroll
        for (int reg = 0; reg < 4; reg++){
          int lrow = w*32 + m*16 + g*4 + reg;
          P0[lrow*64 + ni*16 + l15] = acc_o[m][ni][reg];
        }
    if (l15 == 0){
      #pragma unroll
      for (int m = 0; m < 2; m++)
        #pragma unroll
        for (int reg = 0; reg < 4; reg++){
          int lrow = w*32 + m*16 + g*4 + reg;
          P0[256*64 + lrow] = l_run[m][reg];
        }
    }
  }
}

// combine 2-3 chunks for qt >= 3 (fixed max -> out = sum(acc)/sum(l))
__global__ __launch_bounds__(256) void k_attn_reduce(const float* __restrict__ Pws,
                                                     unsigned short* __restrict__ AO){
  int blk = blockIdx.x;              // 160 = 32 bh x 5 qtp
  int bh = blk / 5, qtp = blk % 5, qt = 3 + qtp;
  int b = bh >> 4, h = bh & 15;
  int nc = qtp < 3 ? 2 : 3;
  const size_t stride = 256*65;
  const float* base = Pws + ((size_t)(bh*5 + qtp)*3) * stride;
  int tid = threadIdx.x;
  #pragma unroll 4
  for (int i = 0; i < 64; i++){
    int idx = i*256 + tid;           // row*64 + d
    int row = idx >> 6, d = idx & 63;
    float l = base[stride*0 + 256*64 + row] + base[stride*1 + 256*64 + row];
    float o = base[stride*0 + idx] + base[stride*1 + idx];
    if (nc == 3){
      l += base[stride*2 + 256*64 + row];
      o += base[stride*2 + idx];
    }
    AO[((size_t)(b*2048 + qt*256 + row)) * 1024 + h*64 + d] = f2b(o / l);
  }
}

// ---------------- launch ----------------

extern "C" void kernel_launch(void* const* d_in, const int* in_sizes, int n_in,
                              void* d_out, int out_size, void* d_ws, size_t ws_size,
                              hipStream_t stream){
  const float* x    = (const float*)d_in[0];
  const float* fqk  = (const float*)d_in[1];
  const float* fv   = (const float*)d_in[2];
  const float* rqk  = (const float*)d_in[3];
  const float* rv   = (const float*)d_in[4];
  const float* fwQ  = (const float*)d_in[5];
  const float* fwK  = (const float*)d_in[6];
  const float* fwV  = (const float*)d_in[7];
  const float* rwQ  = (const float*)d_in[8];
  const float* rwK  = (const float*)d_in[9];
  const float* rwV  = (const float*)d_in[10];
  const float* wo   = (const float*)d_in[11];
  float* out = (float*)d_out;

  char* ws = (char*)d_ws;
  size_t off = 0;
  auto alloc = [&](size_t bytes)->void*{
    void* p = ws + off; off += (bytes + 255) & ~(size_t)255; return p;
  };
  unsigned short* FqkT = (unsigned short*)alloc(1024ull*1024*2);
  unsigned short* FvT  = (unsigned short*)alloc(1024ull*1024*2);
  unsigned short* RqkT = (unsigned short*)alloc(1024ull*1024*2);
  unsigned short* RvT  = (unsigned short*)alloc(1024ull*1024*2);
  unsigned short* WOT  = (unsigned short*)alloc(1024ull*1024*2);
  char* overlay = ws + off;
  unsigned short* Xbf  = (unsigned short*)alloc(4096ull*1024*2);
  unsigned short* AHqk = (unsigned short*)alloc(4096ull*1024*2);
  unsigned short* AHv  = (unsigned short*)alloc(4096ull*1024*2);
  unsigned short* Gq   = (unsigned short*)alloc(4096ull*1024*2);
  unsigned short* Gk   = (unsigned short*)alloc(4096ull*1024*2);
  unsigned short* Gv   = (unsigned short*)alloc(4096ull*1024*2);
  unsigned short* Qp   = (unsigned short*)alloc(4096ull*1024*2);
  unsigned short* Kp   = (unsigned short*)alloc(4096ull*1024*2);
  unsigned short* Vpk  = (unsigned short*)alloc(4096ull*1024*2);
  unsigned short* Vtl  = (unsigned short*)alloc(32ull*16*64*128*2);
  unsigned short* AOm  = (unsigned short*)alloc(4096ull*1024*2);
  float* Pws = (float*)overlay;  // 32*5*3 * 256*65 f32 = 32MB < 48MB overlay

  // fused pack/cast/LDS-tiled transpose (4096 cast blocks + 5120 tile blocks)
  k_prep<<<9216, 256, 0, stream>>>(x, Xbf, fqk, FqkT, fv, FvT, rqk, RqkT, rv, RvT, wo, WOT);

  // feature GEMMs: all_h = X @ F^T  (2 jobs)
  k_gemm_bt3<1,128><<<512, 256, 0, stream>>>(Xbf, FqkT, AHqk, Xbf, FvT, AHv,
                                             nullptr, nullptr, nullptr);
  // fused weighted mix + rank-1 expansion
  k_mix<<<4096, 128, 0, stream>>>(AHqk, AHv, fwQ, fwK, fwV, rwQ, rwK, rwV, Gq, Gk, Gv);
  // restore GEMMs -> head-packed Q/K/V
  k_gemm_bt3<2,128><<<768, 256, 0, stream>>>(Gq, RqkT, Qp, Gk, RqkT, Kp, Gv, RvT, Vpk);
  // V tiling
  k_transpose_v<<<16384, 256, 0, stream>>>(Vpk, Vtl);
  // causal flash attention (480 blocks x 512 thr)
  k_attn<<<480, 512, 0, stream>>>(Qp, Kp, Vtl, AOm, Pws);
  k_attn_reduce<<<160, 256, 0, stream>>>(Pws, AOm);
  // output projection (BN=64 -> 512 blocks)
  k_gemm_bt3<0,64><<<512, 256, 0, stream>>>(AOm, WOT, out,
                                            nullptr, nullptr, nullptr,
                                            nullptr, nullptr, nullptr);
}

// Round 10
// 215.344 us; speedup vs baseline: 1.1235x; 1.1235x over previous
//
#include <hip/hip_runtime.h>
#include <stdint.h>

typedef __attribute__((ext_vector_type(8))) __bf16 bf16x8;
typedef __attribute__((ext_vector_type(4))) float f32x4;
typedef __attribute__((ext_vector_type(4))) unsigned short us4;
typedef __attribute__((ext_vector_type(8))) unsigned short us8v;

__device__ __forceinline__ unsigned short f2b(float f){
  unsigned int u = __builtin_bit_cast(unsigned int, f);
  unsigned int r = (u + 0x7fffu + ((u >> 16) & 1u)) >> 16;
  return (unsigned short)r;
}
// fast round-biased f32->bf16 (error <= 2^-9, used for P only)
__device__ __forceinline__ unsigned short f2b_fast(float f){
  unsigned int u = __builtin_bit_cast(unsigned int, f);
  return (unsigned short)((u + 0x8000u) >> 16);
}
__device__ __forceinline__ float b2f(unsigned short h){
  unsigned int u = ((unsigned int)h) << 16;
  return __builtin_bit_cast(float, u);
}

#define KDIM 1024
#define NDIM 1024

// ---------------- fused prep: x cast + 5 LDS-tiled transposes ----------------
__global__ __launch_bounds__(256) void k_prep(
    const float* __restrict__ x,   unsigned short* __restrict__ Xbf,
    const float* __restrict__ fqk, unsigned short* __restrict__ FqkT,
    const float* __restrict__ fv,  unsigned short* __restrict__ FvT,
    const float* __restrict__ rqk, unsigned short* __restrict__ RqkT,
    const float* __restrict__ rv,  unsigned short* __restrict__ RvT,
    const float* __restrict__ wo,  unsigned short* __restrict__ WOT)
{
  __shared__ float tile[32][33];
  int blk = blockIdx.x;
  int tid = threadIdx.x;
  if (blk < 4096){
    int idx = blk * 256 + tid;
    float4 v = ((const float4*)x)[idx];
    us4 o; o.x = f2b(v.x); o.y = f2b(v.y); o.z = f2b(v.z); o.w = f2b(v.w);
    ((us4*)Xbf)[idx] = o;
    return;
  }
  int t = blk - 4096;
  int mid = t >> 10;
  int within = t & 1023;
  const float* src; unsigned short* dst;
  int b, R, C, tr, tc;
  if (mid < 2){
    src = mid == 0 ? fqk : fv;  dst = mid == 0 ? FqkT : FvT;
    R = 1024; C = 128;
    b = within >> 7; int tw = within & 127; tr = tw >> 2; tc = tw & 3;
  } else {
    src = mid == 2 ? rqk : (mid == 3 ? rv : wo);
    dst = mid == 2 ? RqkT : (mid == 3 ? RvT : WOT);
    R = 1024; C = 1024;
    b = 0; tr = within >> 5; tc = within & 31;
  }
  int r = tid >> 3, c0 = (tid & 7) * 4;
  size_t base = (size_t)b * R * C;
  float4 v = *(const float4*)&src[base + (size_t)(tr*32 + r) * C + tc*32 + c0];
  tile[r][c0+0] = v.x; tile[r][c0+1] = v.y; tile[r][c0+2] = v.z; tile[r][c0+3] = v.w;
  __syncthreads();
  us4 o;
  o.x = f2b(tile[c0+0][r]); o.y = f2b(tile[c0+1][r]);
  o.z = f2b(tile[c0+2][r]); o.w = f2b(tile[c0+3][r]);
  *(us4*)&dst[base + (size_t)(tc*32 + r) * R + tr*32 + c0] = o;
}

// fused mix
__global__ __launch_bounds__(128) void k_mix(const unsigned short* __restrict__ ahqk,
    const unsigned short* __restrict__ ahv,
    const float* __restrict__ fwq, const float* __restrict__ fwk, const float* __restrict__ fwv,
    const float* __restrict__ rwq, const float* __restrict__ rwk, const float* __restrict__ rwv,
    unsigned short* __restrict__ gq, unsigned short* __restrict__ gk, unsigned short* __restrict__ gv){
  int bs = blockIdx.x; int r = threadIdx.x;
  const unsigned short* aq = ahqk + (size_t)bs * 1024;
  const unsigned short* av = ahv  + (size_t)bs * 1024;
  float hq = 0.f, hk = 0.f, hv = 0.f;
  float fq[8], fk[8], fvv[8], rq[8], rk[8], rvv[8];
  #pragma unroll
  for (int n = 0; n < 8; n++){
    fq[n] = fwq[bs*8+n]; fk[n] = fwk[bs*8+n]; fvv[n] = fwv[bs*8+n];
    rq[n] = rwq[bs*8+n]; rk[n] = rwk[bs*8+n]; rvv[n] = rwv[bs*8+n];
  }
  #pragma unroll
  for (int n = 0; n < 8; n++){
    float a = b2f(aq[n*128 + r]); hq += a * fq[n]; hk += a * fk[n];
    hv += b2f(av[n*128 + r]) * fvv[n];
  }
  #pragma unroll
  for (int n = 0; n < 8; n++){
    gq[(size_t)bs*1024 + n*128 + r] = f2b(rq[n] * hq);
    gk[(size_t)bs*1024 + n*128 + r] = f2b(rk[n] * hk);
    gv[(size_t)bs*1024 + n*128 + r] = f2b(rvv[n] * hv);
  }
}

// Vpack [bh][s][64] -> Vtile [bh][t=s/128][dh][128], LDS-tiled coalesced
// 4096 blocks: (bh, t128, 4 s-chunks x 2 dh-chunks)
__global__ __launch_bounds__(256) void k_transpose_v(const unsigned short* __restrict__ Vp,
                                                     unsigned short* __restrict__ Vt){
  __shared__ unsigned short tile[32][36];
  int blk = blockIdx.x;
  int bh = blk >> 7, rem = blk & 127;
  int t = rem >> 3, tl = rem & 7, ts = tl >> 1, td = tl & 1;
  int tid = threadIdx.x;
  int r = tid >> 3, c0 = (tid & 7) * 4;
  // read: rows = s, cols = dh
  us4 v = *(const us4*)&Vp[((size_t)(bh*2048 + t*128 + ts*32 + r)) * 64 + td*32 + c0];
  *(us4*)&tile[r][c0] = v;
  __syncthreads();
  us4 o;
  o.x = tile[c0+0][r]; o.y = tile[c0+1][r]; o.z = tile[c0+2][r]; o.w = tile[c0+3][r];
  *(us4*)&Vt[((size_t)((bh*16 + t)*64 + td*32 + r)) * 128 + ts*32 + c0] = o;
}

// ---------------- GEMM: C[M,N] = A[M,K] @ Bt[N,K]^T, bf16 in, f32 acc ----------------

__device__ __forceinline__ void load_lds16(const void* g, void* l){
  __builtin_amdgcn_global_load_lds((const __attribute__((address_space(1))) unsigned int*)g,
                                   (__attribute__((address_space(3))) unsigned int*)l, 16, 0, 0);
}

template<int OUT_MODE, int BN>
__global__ __launch_bounds__(256) void k_gemm_bt3(
    const unsigned short* __restrict__ A0, const unsigned short* __restrict__ B0, void* __restrict__ C0,
    const unsigned short* __restrict__ A1, const unsigned short* __restrict__ B1, void* __restrict__ C1,
    const unsigned short* __restrict__ A2, const unsigned short* __restrict__ B2, void* __restrict__ C2)
{
  __shared__ unsigned short Al[2][128*32];
  __shared__ unsigned short Bl[2][BN*32];
  // XCD-aware swizzle: contiguous chunk of tiles per XCD (grid % 8 == 0)
  int nb8 = gridDim.x >> 3;
  int swz = (blockIdx.x & 7) * nb8 + (blockIdx.x >> 3);
  int job, bid;
  if constexpr (BN == 64){ job = 0; bid = swz; }
  else { job = swz >> 8; bid = swz & 255; }
  const unsigned short* A  = job == 0 ? A0 : (job == 1 ? A1 : A2);
  const unsigned short* Bt = job == 0 ? B0 : (job == 1 ? B1 : B2);
  void* C = job == 0 ? C0 : (job == 1 ? C1 : C2);
  int bx, by;
  if constexpr (BN == 64){ bx = bid & 15; by = bid >> 4; }
  else { bx = bid & 7; by = bid >> 3; }
  int m0 = by * 128, n0 = bx * BN;
  int tid = threadIdx.x, wid = tid >> 6, lane = tid & 63, l15 = lane & 15, g = lane >> 4;
  int wr = wid >> 1, wc = wid & 1;
  constexpr int WCN = BN / 2;
  constexpr int NACC = WCN / 16;

  auto stage = [&](int buf, int kt){
    #pragma unroll
    for (int i = 0; i < 2; i++){
      int c = i * 256 + tid;
      load_lds16(A + (size_t)(m0 + (c >> 2)) * KDIM + kt * 32 + (c & 3) * 8,
                 &Al[buf][(i * 256 + wid * 64) * 8]);
    }
    #pragma unroll
    for (int i = 0; i < BN/64; i++){
      int c = i * 256 + tid;
      load_lds16(Bt + (size_t)(n0 + (c >> 2)) * KDIM + kt * 32 + (c & 3) * 8,
                 &Bl[buf][(i * 256 + wid * 64) * 8]);
    }
  };

  f32x4 acc[4][NACC] = {};

  stage(0, 0);
  __syncthreads();
  int cur = 0;
  const int nk = KDIM / 32;
  for (int kt = 0; kt < nk; ++kt){
    if (kt + 1 < nk) stage(cur ^ 1, kt + 1);
    bf16x8 af[4], bfv[NACC];
    #pragma unroll
    for (int mi = 0; mi < 4; mi++)
      af[mi] = *(const bf16x8*)&Al[cur][(wr*64 + mi*16 + l15) * 32 + g * 8];
    #pragma unroll
    for (int ni = 0; ni < NACC; ni++)
      bfv[ni] = *(const bf16x8*)&Bl[cur][(wc*WCN + ni*16 + l15) * 32 + g * 8];
    #pragma unroll
    for (int mi = 0; mi < 4; mi++)
      #pragma unroll
      for (int ni = 0; ni < NACC; ni++)
        acc[mi][ni] = __builtin_amdgcn_mfma_f32_16x16x32_bf16(af[mi], bfv[ni], acc[mi][ni], 0, 0, 0);
    __syncthreads();
    cur ^= 1;
  }

  #pragma unroll
  for (int mi = 0; mi < 4; mi++){
    #pragma unroll
    for (int reg = 0; reg < 4; reg++){
      int row = m0 + wr*64 + mi*16 + g*4 + reg;
      #pragma unroll
      for (int ni = 0; ni < NACC; ni++){
        int col = n0 + wc*WCN + ni*16 + l15;
        float v = acc[mi][ni][reg];
        if (OUT_MODE == 0){
          ((float*)C)[(size_t)row * NDIM + col] = v;
        } else if (OUT_MODE == 1){
          ((unsigned short*)C)[(size_t)row * NDIM + col] = f2b(v);
        } else {
          int b = row >> 11, s = row & 2047, h = col >> 6, dh = col & 63;
          ((unsigned short*)C)[(((size_t)(b*16 + h)) * 2048 + s) * 64 + dh] = f2b(v);
        }
      }
    }
  }
}

// ---------------- causal flash attention: QBLK=256, 8 waves, LDS-shared K/V ----------------
// XCD swizzle: 480 blocks = 8 XCDs x 60; 60 = 4 bh x 15 slots -> each XCD's L2
// caches only its 4 heads' K/V (2MB < 4MB L2).
#define PSTR 72
__global__ __launch_bounds__(512) void k_attn(
    const unsigned short* __restrict__ Qp_, const unsigned short* __restrict__ Kp_,
    const unsigned short* __restrict__ Vt, unsigned short* __restrict__ AO,
    float* __restrict__ Pws)
{
  __shared__ unsigned short Klds[2][4096];
  __shared__ unsigned short Vlds[2][4096];
  __shared__ unsigned short Plds[8][32*PSTR];

  int xb = (blockIdx.x & 7) * 60 + (blockIdx.x >> 3);
  int bh = xb / 15;
  int slot = xb % 15;
  int qt, c;
  if (slot < 3){ qt = slot; c = 0; }
  else if (slot < 9){ int s = slot - 3; qt = 3 + (s >> 1); c = s & 1; }
  else { int s = slot - 9; qt = 6 + (s >= 3 ? 1 : 0); c = (s >= 3) ? s - 3 : s; }
  int nc = qt < 3 ? 1 : (qt < 6 ? 2 : 3);
  int b = bh >> 4, h = bh & 15;
  int q0 = qt * 256;
  int kv_lo = c * 768;
  int kv_hi = min((c + 1) * 768, q0 + 256);
  int niter = (kv_hi - kv_lo) >> 6;

  int tid = threadIdx.x, w = tid >> 6, lane = tid & 63, l15 = lane & 15, g = lane >> 4;
  const unsigned short* Qw = Qp_ + ((size_t)bh * 2048 + q0 + w*32) * 64;
  const unsigned short* Kb = Kp_ + (size_t)bh * 2048 * 64;
  const unsigned short* Vb = Vt + (size_t)bh * 16 * 64 * 128;
  unsigned short* Pw = &Plds[w][0];

  int srow = tid >> 3, sj = tid & 7;

  bf16x8 aq[2][2];
  #pragma unroll
  for (int m = 0; m < 2; m++)
    #pragma unroll
    for (int kk = 0; kk < 2; kk++)
      aq[m][kk] = *(const bf16x8*)(Qw + (m*16 + l15)*64 + kk*32 + g*8);

  const float cs = 0.125f;            // natural-log domain for __expf
  float l_run[2][4] = {};
  f32x4 acc_o[2][4] = {};

  us8v kA, vA, kB, vB;

  auto issue = [&](us8v& k0, us8v& v0, int kv0){
    k0 = *(const us8v*)(Kb + ((size_t)(kv0 + srow)) * 64 + sj*8);
    int t128 = kv0 >> 7, koff = kv0 & 64;
    v0 = *(const us8v*)(Vb + ((size_t)(t128*64 + srow)) * 128 + koff + sj*8);
  };
  auto put = [&](int buf, us8v k0, us8v v0){
    *(us8v*)&Klds[buf][(sj*64 + srow)*8] = k0;
    *(us8v*)&Vlds[buf][(sj*64 + srow)*8] = v0;
  };
  auto compute = [&](int buf, int kv0){
    f32x4 s[2][4] = {};
    __builtin_amdgcn_s_setprio(1);
    #pragma unroll
    for (int ti = 0; ti < 4; ti++){
      #pragma unroll
      for (int kk = 0; kk < 2; kk++){
        bf16x8 kf = *(const bf16x8*)&Klds[buf][((kk*4 + g)*64 + ti*16 + l15)*8];
        s[0][ti] = __builtin_amdgcn_mfma_f32_16x16x32_bf16(aq[0][kk], kf, s[0][ti], 0, 0, 0);
        s[1][ti] = __builtin_amdgcn_mfma_f32_16x16x32_bf16(aq[1][kk], kf, s[1][ti], 0, 0, 0);
      }
    }
    __builtin_amdgcn_s_setprio(0);
    bool partial = (kv0 + 64 > q0);
    #pragma unroll
    for (int m = 0; m < 2; m++){
      #pragma unroll
      for (int reg = 0; reg < 4; reg++){
        int row = q0 + w*32 + m*16 + g*4 + reg;
        #pragma unroll
        for (int ti = 0; ti < 4; ti++){
          float x = s[m][ti][reg] * cs;
          if (partial){
            int col = kv0 + ti*16 + l15;
            if (col > row) x = -1e30f;
          }
          float p = __expf(x);
          l_run[m][reg] += p;
          Pw[(m*16 + g*4 + reg)*PSTR + ((ti ^ g)*16) + l15] = f2b_fast(p);
        }
      }
    }
    bf16x8 pa[2][2];
    #pragma unroll
    for (int m = 0; m < 2; m++)
      #pragma unroll
      for (int cc = 0; cc < 2; cc++){
        int tiL = cc*2 + (g >> 1);
        int tiS = tiL ^ ((l15 >> 2) & 3);
        pa[m][cc] = *(const bf16x8*)&Pw[(m*16 + l15)*PSTR + tiS*16 + (g & 1)*8];
      }
    __builtin_amdgcn_s_setprio(1);
    #pragma unroll
    for (int ni = 0; ni < 4; ni++){
      #pragma unroll
      for (int cc = 0; cc < 2; cc++){
        bf16x8 vf = *(const bf16x8*)&Vlds[buf][((cc*4 + g)*64 + ni*16 + l15)*8];
        acc_o[0][ni] = __builtin_amdgcn_mfma_f32_16x16x32_bf16(pa[0][cc], vf, acc_o[0][ni], 0, 0, 0);
        acc_o[1][ni] = __builtin_amdgcn_mfma_f32_16x16x32_bf16(pa[1][cc], vf, acc_o[1][ni], 0, 0, 0);
      }
    }
    __builtin_amdgcn_s_setprio(0);
  };

  issue(kA, vA, kv_lo);
  put(0, kA, vA);
  __syncthreads();
  int it = 0, cur = 0;
  while (true){
    if (it + 1 < niter) issue(kB, vB, kv_lo + (it+1)*64);
    compute(cur, kv_lo + it*64);
    if (it + 1 < niter) put(cur ^ 1, kB, vB);
    __syncthreads();
    cur ^= 1; ++it;
    if (it >= niter) break;
    if (it + 1 < niter) issue(kA, vA, kv_lo + (it+1)*64);
    compute(cur, kv_lo + it*64);
    if (it + 1 < niter) put(cur ^ 1, kA, vA);
    __syncthreads();
    cur ^= 1; ++it;
    if (it >= niter) break;
  }

  #pragma unroll
  for (int m = 0; m < 2; m++)
    #pragma unroll
    for (int reg = 0; reg < 4; reg++){
      #pragma unroll
      for (int off = 1; off < 16; off <<= 1) l_run[m][reg] += __shfl_xor(l_run[m][reg], off);
    }

  if (nc == 1){
    #pragma unroll
    for (int m = 0; m < 2; m++)
      #pragma unroll
      for (int ni = 0; ni < 4; ni++)
        #pragma unroll
        for (int reg = 0; reg < 4; reg++){
          int row = q0 + w*32 + m*16 + g*4 + reg;
          int dh = ni*16 + l15;
          AO[((size_t)(b*2048 + row)) * 1024 + h*64 + dh] = f2b(acc_o[m][ni][reg] / l_run[m][reg]);
        }
  } else {
    float* P0 = Pws + ((size_t)((bh*5 + (qt - 3))*3 + c)) * (256*65);
    #pragma unroll
    for (int m = 0; m < 2; m++)
      #pragma unroll
      for (int ni = 0; ni < 4; ni++)
        #pragma unroll
        for (int reg = 0; reg < 4; reg++){
          int lrow = w*32 + m*16 + g*4 + reg;
          P0[lrow*64 + ni*16 + l15] = acc_o[m][ni][reg];
        }
    if (l15 == 0){
      #pragma unroll
      for (int m = 0; m < 2; m++)
        #pragma unroll
        for (int reg = 0; reg < 4; reg++){
          int lrow = w*32 + m*16 + g*4 + reg;
          P0[256*64 + lrow] = l_run[m][reg];
        }
    }
  }
}

// combine 2-3 chunks for qt >= 3
__global__ __launch_bounds__(256) void k_attn_reduce(const float* __restrict__ Pws,
                                                     unsigned short* __restrict__ AO){
  int blk = blockIdx.x;
  int bh = blk / 5, qtp = blk % 5, qt = 3 + qtp;
  int b = bh >> 4, h = bh & 15;
  int nc = qtp < 3 ? 2 : 3;
  const size_t stride = 256*65;
  const float* base = Pws + ((size_t)(bh*5 + qtp)*3) * stride;
  int tid = threadIdx.x;
  #pragma unroll 4
  for (int i = 0; i < 64; i++){
    int idx = i*256 + tid;
    int row = idx >> 6, d = idx & 63;
    float l = base[stride*0 + 256*64 + row] + base[stride*1 + 256*64 + row];
    float o = base[stride*0 + idx] + base[stride*1 + idx];
    if (nc == 3){
      l += base[stride*2 + 256*64 + row];
      o += base[stride*2 + idx];
    }
    AO[((size_t)(b*2048 + qt*256 + row)) * 1024 + h*64 + d] = f2b(o / l);
  }
}

// ---------------- launch ----------------

extern "C" void kernel_launch(void* const* d_in, const int* in_sizes, int n_in,
                              void* d_out, int out_size, void* d_ws, size_t ws_size,
                              hipStream_t stream){
  const float* x    = (const float*)d_in[0];
  const float* fqk  = (const float*)d_in[1];
  const float* fv   = (const float*)d_in[2];
  const float* rqk  = (const float*)d_in[3];
  const float* rv   = (const float*)d_in[4];
  const float* fwQ  = (const float*)d_in[5];
  const float* fwK  = (const float*)d_in[6];
  const float* fwV  = (const float*)d_in[7];
  const float* rwQ  = (const float*)d_in[8];
  const float* rwK  = (const float*)d_in[9];
  const float* rwV  = (const float*)d_in[10];
  const float* wo   = (const float*)d_in[11];
  float* out = (float*)d_out;

  char* ws = (char*)d_ws;
  size_t off = 0;
  auto alloc = [&](size_t bytes)->void*{
    void* p = ws + off; off += (bytes + 255) & ~(size_t)255; return p;
  };
  unsigned short* FqkT = (unsigned short*)alloc(1024ull*1024*2);
  unsigned short* FvT  = (unsigned short*)alloc(1024ull*1024*2);
  unsigned short* RqkT = (unsigned short*)alloc(1024ull*1024*2);
  unsigned short* RvT  = (unsigned short*)alloc(1024ull*1024*2);
  unsigned short* WOT  = (unsigned short*)alloc(1024ull*1024*2);
  char* overlay = ws + off;
  unsigned short* Xbf  = (unsigned short*)alloc(4096ull*1024*2);
  unsigned short* AHqk = (unsigned short*)alloc(4096ull*1024*2);
  unsigned short* AHv  = (unsigned short*)alloc(4096ull*1024*2);
  unsigned short* Gq   = (unsigned short*)alloc(4096ull*1024*2);
  unsigned short* Gk   = (unsigned short*)alloc(4096ull*1024*2);
  unsigned short* Gv   = (unsigned short*)alloc(4096ull*1024*2);
  unsigned short* Qp   = (unsigned short*)alloc(4096ull*1024*2);
  unsigned short* Kp   = (unsigned short*)alloc(4096ull*1024*2);
  unsigned short* Vpk  = (unsigned short*)alloc(4096ull*1024*2);
  unsigned short* Vtl  = (unsigned short*)alloc(32ull*16*64*128*2);
  unsigned short* AOm  = (unsigned short*)alloc(4096ull*1024*2);
  float* Pws = (float*)overlay;

  k_prep<<<9216, 256, 0, stream>>>(x, Xbf, fqk, FqkT, fv, FvT, rqk, RqkT, rv, RvT, wo, WOT);

  k_gemm_bt3<1,128><<<512, 256, 0, stream>>>(Xbf, FqkT, AHqk, Xbf, FvT, AHv,
                                             nullptr, nullptr, nullptr);
  k_mix<<<4096, 128, 0, stream>>>(AHqk, AHv, fwQ, fwK, fwV, rwQ, rwK, rwV, Gq, Gk, Gv);
  k_gemm_bt3<2,128><<<768, 256, 0, stream>>>(Gq, RqkT, Qp, Gk, RqkT, Kp, Gv, RvT, Vpk);
  k_transpose_v<<<4096, 256, 0, stream>>>(Vpk, Vtl);
  k_attn<<<480, 512, 0, stream>>>(Qp, Kp, Vtl, AOm, Pws);
  k_attn_reduce<<<160, 256, 0, stream>>>(Pws, AOm);
  k_gemm_bt3<0,64><<<512, 256, 0, stream>>>(AOm, WOT, out,
                                            nullptr, nullptr, nullptr,
                                            nullptr, nullptr, nullptr);
}